// Round 3
// baseline (1291.790 us; speedup 1.0000x reference)
//
#include <hip/hip_runtime.h>

#define PI_F 3.14159265358979f
#define MT 16384   // B*T
#define EE 1024    // E
#define FF 4096    // 4E
#define NCH 8      // T-chunks for kv partial reduction
#define CHT (4096 / NCH)

typedef unsigned short u16;
typedef __attribute__((ext_vector_type(8))) short short8;
typedef __attribute__((ext_vector_type(4))) float f32x4;

__device__ __forceinline__ float bf2f(u16 u) {
  unsigned int v = ((unsigned int)u) << 16;
  float f;
  __builtin_memcpy(&f, &v, 4);
  return f;
}
__device__ __forceinline__ u16 f2bf(float f) {
  unsigned int x;
  __builtin_memcpy(&x, &f, 4);
  unsigned int r = x + 0x7fffu + ((x >> 16) & 1u);
  return (u16)(r >> 16);
}
// load element i from an external buffer whose dtype is runtime-detected
__device__ __forceinline__ float ldin(const void* p, long i, int f32) {
  return f32 ? ((const float*)p)[i] : bf2f(((const u16*)p)[i]);
}
// async global->LDS, 16B/lane; LDS dest = wave-uniform base + lane*16B
__device__ __forceinline__ void async16(const u16* g, u16* l) {
  __builtin_amdgcn_global_load_lds(
      (const __attribute__((address_space(1))) unsigned int*)g,
      (__attribute__((address_space(3))) unsigned int*)l, 16, 0, 0);
}

// ---------------------------------------------------------------------------
// dtype probe: bf16 N(0,1) data has no extreme-exponent u16s; fp32 data's low
// mantissa halves are ~uniform u16s -> ~45% extreme. flag: 0=bf16, 1=fp32.
// ---------------------------------------------------------------------------
__global__ __launch_bounds__(256) void detect_dtype(const u16* __restrict__ x,
                                                    int* __restrict__ flag) {
  const int tid = threadIdx.x;
  int cnt = 0;
  for (int i = tid; i < 2048; i += 256) {
    const int e = (x[i] >> 7) & 0xFF;
    if (e == 0 || e >= 0x90) cnt++;
  }
#pragma unroll
  for (int o = 32; o > 0; o >>= 1) cnt += __shfl_xor(cnt, o);
  __shared__ int s[4];
  if ((tid & 63) == 0) s[tid >> 6] = cnt;
  __syncthreads();
  if (tid == 0) flag[0] = (s[0] + s[1] + s[2] + s[3] > 200) ? 1 : 0;
}

// ---------------------------------------------------------------------------
// transpose + convert external weight: src[R][C] (bf16/f32 per flag) ->
// dst[C][R] bf16. block 256, grid (C/64, R/64)
// ---------------------------------------------------------------------------
__global__ __launch_bounds__(256) void transpose_in(
    const void* __restrict__ src, const int* __restrict__ flag,
    u16* __restrict__ dst, int R, int C) {
  __shared__ float tile[64][65];
  const int f = *flag;
  const int tx = threadIdx.x & 63, ty = threadIdx.x >> 6;
  const long c0 = (long)blockIdx.x * 64, r0 = (long)blockIdx.y * 64;
#pragma unroll
  for (int i = 0; i < 16; i++) {
    const int r = ty + i * 4;
    tile[r][tx] = ldin(src, (r0 + r) * (long)C + c0 + tx, f);
  }
  __syncthreads();
#pragma unroll
  for (int i = 0; i < 16; i++) {
    const int cc = ty + i * 4;
    dst[(c0 + cc) * (long)R + r0 + tx] = f2bf(tile[tx][cc]);
  }
}

// concat 3 external bias vectors (len 1024 each) into one f32 [3072]
__global__ __launch_bounds__(256) void concat3(
    const void* __restrict__ a, const void* __restrict__ b,
    const void* __restrict__ c, const int* __restrict__ flag,
    float* __restrict__ out) {
  const int i = blockIdx.x * 256 + threadIdx.x;
  const int fl = *flag;
  if (i < 1024) out[i] = ldin(a, i, fl);
  else if (i < 2048) out[i] = ldin(b, i - 1024, fl);
  else if (i < 3072) out[i] = ldin(c, i - 2048, fl);
}

// ---------------------------------------------------------------------------
// LayerNorm over last dim (1024) -> bf16 out. One block per row.
// xmode: 0 = bf16 ws buffer, 1 = f32 ws buffer, 2 = external (per flag)
// ---------------------------------------------------------------------------
__global__ __launch_bounds__(256) void ln_kernel(
    const void* __restrict__ xin, int xmode, const int* __restrict__ flag,
    const void* __restrict__ w, const void* __restrict__ b,
    u16* __restrict__ out) {
  const long row = blockIdx.x;
  const int tid = threadIdx.x;
  const int fl = *flag;
  const int xf = (xmode == 2) ? fl : xmode;
  float v[4];
  if (xf) {
    const float4 q = ((const float4*)((const float*)xin + row * EE))[tid];
    v[0] = q.x; v[1] = q.y; v[2] = q.z; v[3] = q.w;
  } else {
    const ushort4 u = ((const ushort4*)((const u16*)xin + row * EE))[tid];
    v[0] = bf2f(u.x); v[1] = bf2f(u.y); v[2] = bf2f(u.z); v[3] = bf2f(u.w);
  }
  float sum = v[0] + v[1] + v[2] + v[3];
  float sq = v[0] * v[0] + v[1] * v[1] + v[2] * v[2] + v[3] * v[3];
#pragma unroll
  for (int o = 32; o > 0; o >>= 1) {
    sum += __shfl_xor(sum, o);
    sq += __shfl_xor(sq, o);
  }
  __shared__ float s1[4], s2[4];
  const int wave = tid >> 6, lane = tid & 63;
  if (lane == 0) { s1[wave] = sum; s2[wave] = sq; }
  __syncthreads();
  sum = s1[0] + s1[1] + s1[2] + s1[3];
  sq = s2[0] + s2[1] + s2[2] + s2[3];
  const float mu = sum * (1.f / EE);
  const float var = sq * (1.f / EE) - mu * mu;
  const float rs = rsqrtf(var + 1e-5f);
  ushort4 o4;
  float r0 = (v[0] - mu) * rs * ldin(w, tid * 4 + 0, fl) + ldin(b, tid * 4 + 0, fl);
  float r1 = (v[1] - mu) * rs * ldin(w, tid * 4 + 1, fl) + ldin(b, tid * 4 + 1, fl);
  float r2 = (v[2] - mu) * rs * ldin(w, tid * 4 + 2, fl) + ldin(b, tid * 4 + 2, fl);
  float r3 = (v[3] - mu) * rs * ldin(w, tid * 4 + 3, fl) + ldin(b, tid * 4 + 3, fl);
  o4.x = f2bf(r0); o4.y = f2bf(r1); o4.z = f2bf(r2); o4.w = f2bf(r3);
  ((ushort4*)(out + row * EE))[tid] = o4;
}

// ---------------------------------------------------------------------------
// bf16 MFMA GEMM: C = act(A[M,K] @ Bt[N,K]^T + bias) (+res)
// Counted-vmcnt deep pipeline (T4): 4 LDS buffers [128][32] (64 KiB static),
// prefetch depth 3. Per K-tile: issue tile t+3's 4 global_load_lds, compute
// tile t, s_waitcnt vmcnt(8) (waits only tile t+1; 8 loads stay in flight),
// raw s_barrier. Tail keeps counts uniform via clamped dummy re-stages.
// T2: LDS 16B-unit swizzle (unit ^= row&3), pre-swizzled global source for
// the linear global_load_lds dest + swizzled ds_read (both-sides rule).
// T5: setprio around MFMA cluster. T1: XCD-aware block swizzle (nwg%8==0).
// Epilogue: LDS transpose -> 16 consecutive cols/lane, 16B coalesced stores.
// act: 0 none, 1 relu, 2 gelu, 3 relu-if-col<2048 (fused qkv)
// resMode: 0 none, 1 f32 ws, 2 external (flag). outMode: 0 bf16 ws,
// 1 f32 ws, 2 external d_out (flag dtype) at element offset coff,
// 3 plane-major qkv split: planes 0,1 -> Cout + plane*M*1024, plane 2 -> Cv.
// ---------------------------------------------------------------------------
__global__ __launch_bounds__(256, 2) void gemm_bf16(
    const u16* __restrict__ A, const u16* __restrict__ Bt,
    const void* __restrict__ bias, int biasF32,
    const void* __restrict__ res, int resMode,
    void* __restrict__ Cout, void* __restrict__ Cv, int outMode, long coff,
    const int* __restrict__ flag, int M, int N, int K, int act) {
  __shared__ u16 As[4][4096];  // 4 bufs x (128 rows x 32 cols)
  __shared__ u16 Bs[4][4096];
  const int tid = threadIdx.x;
  const int lane = tid & 63;
  const int wave = tid >> 6;
  const int quad = lane >> 4;
  const int l16 = lane & 15;
  const int wm = (wave >> 1) * 64;
  const int wn = (wave & 1) * 64;
  // T1: XCD swizzle (bijective: all our grids have nwg % 8 == 0)
  const int nwg = gridDim.x * gridDim.y;
  const int bid0 = blockIdx.x + gridDim.x * blockIdx.y;
  const int bid = (bid0 & 7) * (nwg >> 3) + (bid0 >> 3);
  const int bx = bid % gridDim.x;
  const int by = bid / gridDim.x;
  const long bm = (long)bx * 128;
  const long bn = (long)by * 128;

  f32x4 acc[4][4];
#pragma unroll
  for (int i = 0; i < 4; i++)
#pragma unroll
    for (int j = 0; j < 4; j++)
#pragma unroll
      for (int r = 0; r < 4; r++) acc[i][j][r] = 0.f;

  // staging: thread t covers row (t>>2) (+64 for pass 1), 16B unit (t&3).
  // T2 both-sides: LDS dest linear; global source column pre-swizzled.
  const int trow = tid >> 2;                    // 0..63
  const int tswz = (tid & 3) ^ (trow & 3);      // logical unit for this slot
  const u16* Ap = A + (bm + trow) * (long)K + tswz * 8;
  const u16* Bp = Bt + (bn + trow) * (long)K + tswz * 8;
  const long rowK64 = 64 * (long)K;

  auto stage = [&](int buf, long kt) {
    u16* Ad = &As[buf][wave * 512];
    u16* Bd = &Bs[buf][wave * 512];
    async16(Ap + kt, Ad);
    async16(Ap + rowK64 + kt, Ad + 2048);
    async16(Bp + kt, Bd);
    async16(Bp + rowK64 + kt, Bd + 2048);
  };
  const int rswz = (quad ^ (l16 & 3)) * 8;  // swizzled ds_read unit offset
  auto compute = [&](int buf) {
    short8 af[4], bfr[4];
#pragma unroll
    for (int i = 0; i < 4; i++)
      af[i] = *(const short8*)&As[buf][(wm + i * 16 + l16) * 32 + rswz];
#pragma unroll
    for (int i = 0; i < 4; i++)
      bfr[i] = *(const short8*)&Bs[buf][(wn + i * 16 + l16) * 32 + rswz];
    __builtin_amdgcn_s_setprio(1);
#pragma unroll
    for (int mi = 0; mi < 4; mi++)
#pragma unroll
      for (int ni = 0; ni < 4; ni++)
        acc[mi][ni] = __builtin_amdgcn_mfma_f32_16x16x32_bf16(
            af[mi], bfr[ni], acc[mi][ni], 0, 0, 0);
    __builtin_amdgcn_s_setprio(0);
  };

  const int nt = K >> 5;
  // prologue: tiles 0,1,2 in flight (12 loads); wait tile 0 (8 remain)
  stage(0, 0);
  stage(1, 32);
  stage(2, 64);
  asm volatile("s_waitcnt vmcnt(8)" ::: "memory");
  __builtin_amdgcn_s_barrier();
  for (int t = 0; t < nt; ++t) {
    const long ts = (t + 3 < nt) ? (long)(t + 3) : (long)(nt - 1);
    stage((t + 3) & 3, ts * 32);  // buf (t+3)&3 free since barrier of t-1
    compute(t & 3);
    asm volatile("s_waitcnt vmcnt(8)" ::: "memory");  // tile t+1 landed
    __builtin_amdgcn_s_barrier();
  }
  __syncthreads();  // drain dummies (vmcnt 0) before LDS reuse

  // ---- epilogue: bias+act in frag domain, LDS transpose, coalesced store
  const int fl = *flag;
  const long Nl = N;
  float bv4[4];
  long gcA[4];
#pragma unroll
  for (int ni = 0; ni < 4; ni++) {
    gcA[ni] = bn + wn + ni * 16 + l16;
    bv4[ni] = biasF32 ? ((const float*)bias)[gcA[ni]] : ldin(bias, gcA[ni], fl);
  }
#pragma unroll
  for (int mi = 0; mi < 4; mi++)
#pragma unroll
    for (int ni = 0; ni < 4; ni++)
#pragma unroll
      for (int r = 0; r < 4; r++) {
        float v = acc[mi][ni][r] + bv4[ni];
        if (act == 1 || (act == 3 && gcA[ni] < 2048)) v = fmaxf(v, 0.f);
        else if (act == 2) v = 0.5f * v * (1.f + erff(v * 0.70710678118654752f));
        acc[mi][ni][r] = v;
      }
  float* sf = (float*)&As[0][0] + wave * 1088;  // 16x68 f32 per wave, disjoint
  const int er = lane >> 2;        // 0..15 row within 16-row slab
  const int ec = (lane & 3) * 16;  // 16-col run
#pragma unroll
  for (int mi = 0; mi < 4; mi++) {
#pragma unroll
    for (int ni = 0; ni < 4; ni++)
#pragma unroll
      for (int r = 0; r < 4; r++)
        sf[(quad * 4 + r) * 68 + ni * 16 + l16] = acc[mi][ni][r];
    // same-wave DS in-order + self-overlapping addresses => ordered
    f32x4 w0 = *(const f32x4*)&sf[er * 68 + ec + 0];
    f32x4 w1 = *(const f32x4*)&sf[er * 68 + ec + 4];
    f32x4 w2 = *(const f32x4*)&sf[er * 68 + ec + 8];
    f32x4 w3 = *(const f32x4*)&sf[er * 68 + ec + 12];
    const long gr = bm + wm + mi * 16 + er;
    const long gc0 = bn + wn + ec;
    const long ib = gr * Nl + gc0;
    if (resMode == 1 || (resMode == 2 && fl)) {
      const f32x4* rp = (const f32x4*)((const float*)res + ib);
      f32x4 r0 = rp[0], r1 = rp[1], r2 = rp[2], r3 = rp[3];
#pragma unroll
      for (int j = 0; j < 4; j++) {
        w0[j] += r0[j]; w1[j] += r1[j]; w2[j] += r2[j]; w3[j] += r3[j];
      }
    } else if (resMode == 2) {
      const short8* rp = (const short8*)((const u16*)res + ib);
      short8 ra = rp[0], rb = rp[1];
#pragma unroll
      for (int j = 0; j < 4; j++) {
        w0[j] += bf2f((u16)ra[j]);
        w1[j] += bf2f((u16)ra[j + 4]);
        w2[j] += bf2f((u16)rb[j]);
        w3[j] += bf2f((u16)rb[j + 4]);
      }
    }
    if (outMode == 1 || (outMode == 2 && fl)) {
      f32x4* op = (f32x4*)((float*)Cout + coff + ib);
      op[0] = w0; op[1] = w1; op[2] = w2; op[3] = w3;
    } else {
      u16 tmp[16];
#pragma unroll
      for (int j = 0; j < 4; j++) {
        tmp[j] = f2bf(w0[j]);
        tmp[j + 4] = f2bf(w1[j]);
        tmp[j + 8] = f2bf(w2[j]);
        tmp[j + 12] = f2bf(w3[j]);
      }
      u16* op;
      if (outMode == 3) {
        const int plane = (int)(bn >> 10);
        u16* dst = (plane == 2) ? (u16*)Cv
                                : ((u16*)Cout + plane * ((long)M << 10));
        op = dst + (gr << 10) + (gc0 & 1023);
      } else {
        op = (u16*)Cout + coff + ib;
      }
      *(short8*)op = *(short8*)&tmp[0];
      *(short8*)(op + 8) = *(short8*)&tmp[8];
    }
  }
}

// ---------------------------------------------------------------------------
// kv partial: per (bh, chunk) accumulate kv_s/kv_c [64x64], ksum_s/c [64]
// kvpart[ch][bh][2][64][64], kspart[ch][bh][2][64]
// ---------------------------------------------------------------------------
__global__ __launch_bounds__(256) void kv_partial(
    const u16* __restrict__ k, const u16* __restrict__ v,
    float* __restrict__ kvpart, float* __restrict__ kspart) {
  const int bh = blockIdx.x;  // 0..63
  const int ch = blockIdx.y;  // 0..NCH-1
  const int b = bh >> 4, h = bh & 15;
  const int tid = threadIdx.x;
  __shared__ float kl[8][64], vl[8][64];
  const int dkq = tid >> 4;  // 0..15
  const int dvq = tid & 15;  // 0..15
  float accS[4][4] = {}, accC[4][4] = {};
  float ksS[4] = {}, ksC[4] = {};
  const int tt = tid >> 5;        // 0..7
  const int cc = (tid & 31) * 2;  // 0..62
  const long base = ((long)b * 4096 + ch * CHT) * EE + h * 64;
  for (int tb = 0; tb < CHT; tb += 8) {
    const long roff = base + (long)(tb + tt) * EE + cc;
    const unsigned int ku = *(const unsigned int*)(k + roff);
    const unsigned int vu = *(const unsigned int*)(v + roff);
    __syncthreads();
    kl[tt][cc] = bf2f((u16)ku);
    kl[tt][cc + 1] = bf2f((u16)(ku >> 16));
    vl[tt][cc] = bf2f((u16)vu);
    vl[tt][cc + 1] = bf2f((u16)(vu >> 16));
    __syncthreads();
#pragma unroll
    for (int j = 0; j < 8; j++) {
      const int t = ch * CHT + tb + j;
      float s, c;
      __sincosf((float)(t + 1) * (PI_F * 0.5f / 4096.f), &s, &c);
      float kk[4], vv[4];
#pragma unroll
      for (int i = 0; i < 4; i++) {
        kk[i] = kl[j][dkq * 4 + i];
        vv[i] = vl[j][dvq * 4 + i];
      }
#pragma unroll
      for (int i = 0; i < 4; i++) {
        const float ks_ = kk[i] * s, kc_ = kk[i] * c;
        ksS[i] += ks_;
        ksC[i] += kc_;
#pragma unroll
        for (int jj = 0; jj < 4; jj++) {
          accS[i][jj] += ks_ * vv[jj];
          accC[i][jj] += kc_ * vv[jj];
        }
      }
    }
  }
  float* outS = kvpart + (((long)ch * 64 + bh) * 2 + 0) * 4096;
  float* outC = outS + 4096;
#pragma unroll
  for (int i = 0; i < 4; i++)
#pragma unroll
    for (int jj = 0; jj < 4; jj++) {
      outS[(dkq * 4 + i) * 64 + dvq * 4 + jj] = accS[i][jj];
      outC[(dkq * 4 + i) * 64 + dvq * 4 + jj] = accC[i][jj];
    }
  if (dvq == 0) {
    float* oS = kspart + ((long)ch * 64 + bh) * 2 * 64;
#pragma unroll
    for (int i = 0; i < 4; i++) {
      oS[dkq * 4 + i] = ksS[i];
      oS[64 + dkq * 4 + i] = ksC[i];
    }
  }
}

// ---------------------------------------------------------------------------
__global__ __launch_bounds__(256) void kv_reduce(
    const float* __restrict__ kvpart, const float* __restrict__ kspart,
    float* __restrict__ kvcomb, float* __restrict__ kscomb) {
  const long KVTOT = 64L * 2 * 4096;  // 524288
  const long KSTOT = 64L * 2 * 64;    // 8192
  const long idx = (long)blockIdx.x * 256 + threadIdx.x;
  if (idx < KVTOT) {
    float s = 0.f;
#pragma unroll
    for (int chn = 0; chn < NCH; chn++) s += kvpart[chn * KVTOT + idx];
    kvcomb[idx] = s;
  } else {
    const long i2 = idx - KVTOT;
    if (i2 < KSTOT) {
      float s = 0.f;
#pragma unroll
      for (int chn = 0; chn < NCH; chn++) s += kspart[chn * KSTOT + i2];
      kscomb[i2] = s;
    }
  }
}

// ---------------------------------------------------------------------------
// apply: out[t,dv] = (s_t*(q.KVs)+c_t*(q.KVc))[dv] / max(s_t*q.kss+c_t*q.ksc,eps)
// ---------------------------------------------------------------------------
__global__ __launch_bounds__(256) void attn_apply(
    const u16* __restrict__ q, const float* __restrict__ kvcomb,
    const float* __restrict__ kscomb, u16* __restrict__ attn) {
  const int bh = blockIdx.x;
  const int b = bh >> 4, h = bh & 15;
  const int t0 = blockIdx.y * 64;
  const int tid = threadIdx.x;
  __shared__ float kvl[2][64][64];
  __shared__ float ksl[2][64];
  __shared__ float ql[64][66];

  const float4* kvsrc = (const float4*)(kvcomb + (long)bh * 8192);
  float4* kvdst = (float4*)&kvl[0][0][0];
#pragma unroll
  for (int i = 0; i < 8; i++) kvdst[tid + 256 * i] = kvsrc[tid + 256 * i];
  if (tid < 32) ((float4*)&ksl[0][0])[tid] = ((const float4*)(kscomb + (long)bh * 128))[tid];
  {
    const int r = tid >> 2;
    const int c = (tid & 3) * 16;
    const u16* qp = q + ((long)b * 4096 + t0 + r) * EE + h * 64 + c;
    const uint4 u0 = *(const uint4*)qp;
    const uint4 u1 = *(const uint4*)(qp + 8);
    unsigned int uu[8] = {u0.x, u0.y, u0.z, u0.w, u1.x, u1.y, u1.z, u1.w};
#pragma unroll
    for (int i = 0; i < 8; i++) {
      ql[r][c + 2 * i] = bf2f((u16)uu[i]);
      ql[r][c + 2 * i + 1] = bf2f((u16)(uu[i] >> 16));
    }
  }
  __syncthreads();

  const int tg = tid >> 4;
  const int dvq = tid & 15;
  const int dv0 = dvq * 4;

  float o1[4][4] = {}, o2[4][4] = {}, zs[4] = {}, zc[4] = {};
  for (int dk = 0; dk < 64; dk++) {
    const float ks0 = ksl[0][dk], ks1 = ksl[1][dk];
    float kv0[4], kv1[4];
#pragma unroll
    for (int j = 0; j < 4; j++) {
      kv0[j] = kvl[0][dk][dv0 + j];
      kv1[j] = kvl[1][dk][dv0 + j];
    }
#pragma unroll
    for (int it = 0; it < 4; it++) {
      const float qv = ql[tg + it * 16][dk];
      zs[it] += qv * ks0;
      zc[it] += qv * ks1;
#pragma unroll
      for (int j = 0; j < 4; j++) {
        o1[it][j] += qv * kv0[j];
        o2[it][j] += qv * kv1[j];
      }
    }
  }
#pragma unroll
  for (int it = 0; it < 4; it++) {
    const int t = t0 + tg + it * 16;
    float s, c;
    __sincosf((float)(t + 1) * (PI_F * 0.5f / 4096.f), &s, &c);
    const float z = s * zs[it] + c * zc[it];
    const float zinv = 1.f / fmaxf(z, 1e-6f);
    ushort4 o4;
    o4.x = f2bf((s * o1[it][0] + c * o2[it][0]) * zinv);
    o4.y = f2bf((s * o1[it][1] + c * o2[it][1]) * zinv);
    o4.z = f2bf((s * o1[it][2] + c * o2[it][2]) * zinv);
    o4.w = f2bf((s * o1[it][3] + c * o2[it][3]) * zinv);
    *(ushort4*)(attn + ((long)b * 4096 + t) * EE + h * 64 + dv0) = o4;
  }
}

// ---------------------------------------------------------------------------
extern "C" void kernel_launch(void* const* d_in, const int* in_sizes, int n_in,
                              void* d_out, int out_size, void* d_ws, size_t ws_size,
                              hipStream_t stream) {
  const void* x = d_in[0];
  const void* ln1w = d_in[1];
  const void* ln1b = d_in[2];
  const void* wq = d_in[3];
  const void* bq = d_in[4];
  const void* wk = d_in[5];
  const void* bk = d_in[6];
  const void* wv = d_in[7];
  const void* bv = d_in[8];
  const void* wo = d_in[9];
  const void* bo = d_in[10];
  const void* ln2w = d_in[11];
  const void* ln2b = d_in[12];
  const void* wfc = d_in[13];
  const void* bfc = d_in[14];
  const void* wproj = d_in[15];
  const void* bproj = d_in[16];

  char* ws = (char*)d_ws;
  size_t off = 0;
  auto alloc = [&](size_t bytes) -> char* {
    char* p = ws + off;
    off += (bytes + 255) & ~((size_t)255);
    return p;
  };
  // footprint identical to the proven 202-MiB baseline layout
  int* flag = (int*)alloc(256);
  u16* wqkvT = (u16*)alloc((size_t)3 * EE * EE * 2);  // [wq^T|wk^T|wv^T] rows
  u16* woT = (u16*)alloc((size_t)EE * EE * 2);
  u16* wfcT = (u16*)alloc((size_t)EE * FF * 2);
  u16* wprojT = (u16*)alloc((size_t)FF * EE * 2);
  float* qkvBias = (float*)alloc(3072 * 4);
  u16* h = (u16*)alloc((size_t)MT * EE * 2);       // 32 MiB
  float* x2 = (float*)alloc((size_t)MT * EE * 4);  // 64 MiB (residual, f32)
  u16* qk2 = (u16*)alloc((size_t)2 * MT * EE * 2); // 64 MiB: q,k planes
  float* kvpart = (float*)alloc((size_t)NCH * 64 * 2 * 64 * 64 * 4);
  float* kspart = (float*)alloc((size_t)NCH * 64 * 2 * 64 * 4);
  float* kvcomb = (float*)alloc((size_t)64 * 2 * 64 * 64 * 4);
  float* kscomb = (float*)alloc((size_t)64 * 2 * 64 * 4);
  const long PL = (long)MT * EE;  // plane stride (elems)
  u16* qb = qk2;            // plane 0
  u16* kb = qk2 + PL;       // plane 1
  u16* vb = (u16*)x2;       // v plane aliases x2[0:32MiB] — x2 dead until WO
                            // gemm, v dead before WO gemm overwrites it
  u16* attnb = kb;          // k-plane dead after kv_partial
  u16* g = qk2;             // q+k planes (64 MiB) dead after WO gemm
  (void)ws_size; (void)in_sizes; (void)n_in; (void)out_size;

  detect_dtype<<<1, 256, 0, stream>>>((const u16*)x, flag);

  transpose_in<<<dim3(16, 16), 256, 0, stream>>>(wq, flag, wqkvT, EE, EE);
  transpose_in<<<dim3(16, 16), 256, 0, stream>>>(wk, flag, wqkvT + (size_t)EE * EE, EE, EE);
  transpose_in<<<dim3(16, 16), 256, 0, stream>>>(wv, flag, wqkvT + (size_t)2 * EE * EE, EE, EE);
  transpose_in<<<dim3(16, 16), 256, 0, stream>>>(wo, flag, woT, EE, EE);
  transpose_in<<<dim3(64, 16), 256, 0, stream>>>(wfc, flag, wfcT, EE, FF);
  transpose_in<<<dim3(16, 64), 256, 0, stream>>>(wproj, flag, wprojT, FF, EE);
  concat3<<<12, 256, 0, stream>>>(bq, bk, bv, flag, qkvBias);

  ln_kernel<<<MT, 256, 0, stream>>>(x, 2, flag, ln1w, ln1b, h);

  // fused QKV: N=3072, relu on q,k planes only; plane-major output
  gemm_bf16<<<dim3(128, 24), 256, 0, stream>>>(h, wqkvT, qkvBias, 1, nullptr, 0,
                                               qk2, vb, 3, 0, flag, MT, 3072, EE, 3);

  kv_partial<<<dim3(64, NCH), 256, 0, stream>>>(kb, vb, kvpart, kspart);
  kv_reduce<<<2080, 256, 0, stream>>>(kvpart, kspart, kvcomb, kscomb);
  attn_apply<<<dim3(64, 64), 256, 0, stream>>>(qb, kvcomb, kscomb, attnb);

  gemm_bf16<<<dim3(128, 8), 256, 0, stream>>>(attnb, woT, bo, 0, x, 2, x2, nullptr,
                                              1, 0, flag, MT, EE, EE, 0);
  ln_kernel<<<MT, 256, 0, stream>>>(x2, 1, flag, ln2w, ln2b, h);

  for (int c = 0; c < 2; c++) {
    const long ro = (long)c * 8192 * EE;
    gemm_bf16<<<dim3(64, 32), 256, 0, stream>>>(h + ro, wfcT, bfc, 0, nullptr, 0,
                                                g, nullptr, 0, 0, flag, 8192, FF, EE, 2);
    gemm_bf16<<<dim3(64, 8), 256, 0, stream>>>(g, wprojT, bproj, 0, x2 + ro, 1,
                                               d_out, nullptr, 2, ro, flag, 8192, EE, FF, 0);
  }
}

// Round 4
// 1131.170 us; speedup vs baseline: 1.1420x; 1.1420x over previous
//
#include <hip/hip_runtime.h>

#define PI_F 3.14159265358979f
#define MT 16384   // B*T
#define EE 1024    // E
#define FF 4096    // 4E
#define NCH 8      // T-chunks for kv partial reduction
#define CHT (4096 / NCH)

typedef unsigned short u16;
typedef __attribute__((ext_vector_type(8))) short short8;
typedef __attribute__((ext_vector_type(4))) float f32x4;

__device__ __forceinline__ float bf2f(u16 u) {
  unsigned int v = ((unsigned int)u) << 16;
  float f;
  __builtin_memcpy(&f, &v, 4);
  return f;
}
__device__ __forceinline__ u16 f2bf(float f) {
  unsigned int x;
  __builtin_memcpy(&x, &f, 4);
  unsigned int r = x + 0x7fffu + ((x >> 16) & 1u);
  return (u16)(r >> 16);
}
// load element i from an external buffer whose dtype is runtime-detected
__device__ __forceinline__ float ldin(const void* p, long i, int f32) {
  return f32 ? ((const float*)p)[i] : bf2f(((const u16*)p)[i]);
}
// async global->LDS, 16B/lane; LDS dest = wave-uniform base + lane*16B
__device__ __forceinline__ void async16(const u16* g, u16* l) {
  __builtin_amdgcn_global_load_lds(
      (const __attribute__((address_space(1))) unsigned int*)g,
      (__attribute__((address_space(3))) unsigned int*)l, 16, 0, 0);
}

// ---------------------------------------------------------------------------
// dtype probe: bf16 N(0,1) data has no extreme-exponent u16s; fp32 data's low
// mantissa halves are ~uniform u16s -> ~45% extreme. flag: 0=bf16, 1=fp32.
// ---------------------------------------------------------------------------
__global__ __launch_bounds__(256) void detect_dtype(const u16* __restrict__ x,
                                                    int* __restrict__ flag) {
  const int tid = threadIdx.x;
  int cnt = 0;
  for (int i = tid; i < 2048; i += 256) {
    const int e = (x[i] >> 7) & 0xFF;
    if (e == 0 || e >= 0x90) cnt++;
  }
#pragma unroll
  for (int o = 32; o > 0; o >>= 1) cnt += __shfl_xor(cnt, o);
  __shared__ int s[4];
  if ((tid & 63) == 0) s[tid >> 6] = cnt;
  __syncthreads();
  if (tid == 0) flag[0] = (s[0] + s[1] + s[2] + s[3] > 200) ? 1 : 0;
}

// ---------------------------------------------------------------------------
// transpose + convert external weight: src[R][C] (bf16/f32 per flag) ->
// dst[C][R] bf16. block 256, grid (C/64, R/64)
// ---------------------------------------------------------------------------
__global__ __launch_bounds__(256) void transpose_in(
    const void* __restrict__ src, const int* __restrict__ flag,
    u16* __restrict__ dst, int R, int C) {
  __shared__ float tile[64][65];
  const int f = *flag;
  const int tx = threadIdx.x & 63, ty = threadIdx.x >> 6;
  const long c0 = (long)blockIdx.x * 64, r0 = (long)blockIdx.y * 64;
#pragma unroll
  for (int i = 0; i < 16; i++) {
    const int r = ty + i * 4;
    tile[r][tx] = ldin(src, (r0 + r) * (long)C + c0 + tx, f);
  }
  __syncthreads();
#pragma unroll
  for (int i = 0; i < 16; i++) {
    const int cc = ty + i * 4;
    dst[(c0 + cc) * (long)R + r0 + tx] = f2bf(tile[tx][cc]);
  }
}

// concat 3 external bias vectors (len 1024 each) into one f32 [3072]
__global__ __launch_bounds__(256) void concat3(
    const void* __restrict__ a, const void* __restrict__ b,
    const void* __restrict__ c, const int* __restrict__ flag,
    float* __restrict__ out) {
  const int i = blockIdx.x * 256 + threadIdx.x;
  const int fl = *flag;
  if (i < 1024) out[i] = ldin(a, i, fl);
  else if (i < 2048) out[i] = ldin(b, i - 1024, fl);
  else if (i < 3072) out[i] = ldin(c, i - 2048, fl);
}

// ---------------------------------------------------------------------------
// LayerNorm over last dim (1024) -> bf16 out. One block per row.
// xmode: 0 = bf16 ws buffer, 1 = f32 ws buffer, 2 = external (per flag)
// ---------------------------------------------------------------------------
__global__ __launch_bounds__(256) void ln_kernel(
    const void* __restrict__ xin, int xmode, const int* __restrict__ flag,
    const void* __restrict__ w, const void* __restrict__ b,
    u16* __restrict__ out) {
  const long row = blockIdx.x;
  const int tid = threadIdx.x;
  const int fl = *flag;
  const int xf = (xmode == 2) ? fl : xmode;
  float v[4];
  if (xf) {
    const float4 q = ((const float4*)((const float*)xin + row * EE))[tid];
    v[0] = q.x; v[1] = q.y; v[2] = q.z; v[3] = q.w;
  } else {
    const ushort4 u = ((const ushort4*)((const u16*)xin + row * EE))[tid];
    v[0] = bf2f(u.x); v[1] = bf2f(u.y); v[2] = bf2f(u.z); v[3] = bf2f(u.w);
  }
  float sum = v[0] + v[1] + v[2] + v[3];
  float sq = v[0] * v[0] + v[1] * v[1] + v[2] * v[2] + v[3] * v[3];
#pragma unroll
  for (int o = 32; o > 0; o >>= 1) {
    sum += __shfl_xor(sum, o);
    sq += __shfl_xor(sq, o);
  }
  __shared__ float s1[4], s2[4];
  const int wave = tid >> 6, lane = tid & 63;
  if (lane == 0) { s1[wave] = sum; s2[wave] = sq; }
  __syncthreads();
  sum = s1[0] + s1[1] + s1[2] + s1[3];
  sq = s2[0] + s2[1] + s2[2] + s2[3];
  const float mu = sum * (1.f / EE);
  const float var = sq * (1.f / EE) - mu * mu;
  const float rs = rsqrtf(var + 1e-5f);
  ushort4 o4;
  float r0 = (v[0] - mu) * rs * ldin(w, tid * 4 + 0, fl) + ldin(b, tid * 4 + 0, fl);
  float r1 = (v[1] - mu) * rs * ldin(w, tid * 4 + 1, fl) + ldin(b, tid * 4 + 1, fl);
  float r2 = (v[2] - mu) * rs * ldin(w, tid * 4 + 2, fl) + ldin(b, tid * 4 + 2, fl);
  float r3 = (v[3] - mu) * rs * ldin(w, tid * 4 + 3, fl) + ldin(b, tid * 4 + 3, fl);
  o4.x = f2bf(r0); o4.y = f2bf(r1); o4.z = f2bf(r2); o4.w = f2bf(r3);
  ((ushort4*)(out + row * EE))[tid] = o4;
}

// ---------------------------------------------------------------------------
// bf16 MFMA GEMM: C = act(A[M,K] @ Bt[N,K]^T + bias) (+res)
// Counted-vmcnt pipeline (T4): 3 LDS buffers [128][32] (48 KiB), prefetch
// depth 2 -> 3 blocks/CU. Per K-tile: issue tile t+2's 4 global_load_lds,
// compute tile t, s_waitcnt vmcnt(4) (tile t+1 landed; t+2 stays in flight),
// raw s_barrier. Never drains to 0 in the loop.
// Block scheduling: GROUP_M=8 supergroup on raw linear bid (robust to any
// XCD assignment): consecutive blocks walk N-panels within an 8-row A-strip
// -> per-L2 working set ~3 MB, A fetched ~once from HBM. (Round-3's XCD
// chunk remap caused 4x FETCH; removed.)
// T2: LDS 16B-unit swizzle (unit ^= row&3) via pre-swizzled global source +
// swizzled ds_read. T5: setprio around MFMA cluster.
// Epilogue: LDS transpose -> 16 consecutive cols/lane, 16B coalesced stores.
// act: 0 none, 1 relu, 2 gelu, 3 relu-if-col<2048 (fused qkv)
// resMode: 0 none, 1 f32 ws, 2 external (flag). outMode: 0 bf16 ws,
// 1 f32 ws, 2 external d_out (flag dtype) at element offset coff,
// 3 plane-major qkv split: planes 0,1 -> Cout + plane*M*1024, plane 2 -> Cv.
// ---------------------------------------------------------------------------
__global__ __launch_bounds__(256, 3) void gemm_bf16(
    const u16* __restrict__ A, const u16* __restrict__ Bt,
    const void* __restrict__ bias, int biasF32,
    const void* __restrict__ res, int resMode,
    void* __restrict__ Cout, void* __restrict__ Cv, int outMode, long coff,
    const int* __restrict__ flag, int M, int N, int K, int act) {
  __shared__ u16 As[3][4096];  // 3 bufs x (128 rows x 32 cols)
  __shared__ u16 Bs[3][4096];
  const int tid = threadIdx.x;
  const int lane = tid & 63;
  const int wave = tid >> 6;
  const int quad = lane >> 4;
  const int l16 = lane & 15;
  const int wm = (wave >> 1) * 64;
  const int wn = (wave & 1) * 64;
  // GROUP_M supergroup: consecutive bids walk by (N) within an 8-row A strip
  const int bid0 = blockIdx.x + gridDim.x * blockIdx.y;
  const int gy = gridDim.y;
  const int width = 8 * gy;             // gridDim.x % 8 == 0 for all our grids
  const int group = bid0 / width;
  const int rem = bid0 - group * width;
  const int bx = group * 8 + (rem & 7);
  const int by = rem >> 3;
  const long bm = (long)bx * 128;
  const long bn = (long)by * 128;

  f32x4 acc[4][4];
#pragma unroll
  for (int i = 0; i < 4; i++)
#pragma unroll
    for (int j = 0; j < 4; j++)
#pragma unroll
      for (int r = 0; r < 4; r++) acc[i][j][r] = 0.f;

  // staging: thread t covers row (t>>2) (+64 for pass 1), 16B unit (t&3).
  // T2 both-sides: LDS dest linear; global source column pre-swizzled.
  const int trow = tid >> 2;                    // 0..63
  const int tswz = (tid & 3) ^ (trow & 3);      // logical unit for this slot
  const u16* Ap = A + (bm + trow) * (long)K + tswz * 8;
  const u16* Bp = Bt + (bn + trow) * (long)K + tswz * 8;
  const long rowK64 = 64 * (long)K;

  auto stage = [&](int buf, long kt) {
    u16* Ad = &As[buf][wave * 512];
    u16* Bd = &Bs[buf][wave * 512];
    async16(Ap + kt, Ad);
    async16(Ap + rowK64 + kt, Ad + 2048);
    async16(Bp + kt, Bd);
    async16(Bp + rowK64 + kt, Bd + 2048);
  };
  const int rswz = (quad ^ (l16 & 3)) * 8;  // swizzled ds_read unit offset
  auto compute = [&](int buf) {
    short8 af[4], bfr[4];
#pragma unroll
    for (int i = 0; i < 4; i++)
      af[i] = *(const short8*)&As[buf][(wm + i * 16 + l16) * 32 + rswz];
#pragma unroll
    for (int i = 0; i < 4; i++)
      bfr[i] = *(const short8*)&Bs[buf][(wn + i * 16 + l16) * 32 + rswz];
    __builtin_amdgcn_s_setprio(1);
#pragma unroll
    for (int mi = 0; mi < 4; mi++)
#pragma unroll
      for (int ni = 0; ni < 4; ni++)
        acc[mi][ni] = __builtin_amdgcn_mfma_f32_16x16x32_bf16(
            af[mi], bfr[ni], acc[mi][ni], 0, 0, 0);
    __builtin_amdgcn_s_setprio(0);
  };

  const int nt = K >> 5;
  // prologue: tiles 0,1 in flight (8 loads); wait tile 0 (4 remain)
  stage(0, 0);
  stage(1, 32);
  asm volatile("s_waitcnt vmcnt(4)" ::: "memory");
  __builtin_amdgcn_s_barrier();
  int cb = 0, sb = 2;
  for (int t = 0; t < nt; ++t) {
    const long ts = (t + 2 < nt) ? (long)(t + 2) * 32 : (long)(nt - 1) * 32;
    stage(sb, ts);   // buf sb held tile t-1 (dead since barrier of t-1)
    compute(cb);     // ds_read + MFMA current tile (landed)
    asm volatile("s_waitcnt vmcnt(4)" ::: "memory");  // tile t+1 landed
    __builtin_amdgcn_s_barrier();
    cb = (cb == 2) ? 0 : cb + 1;
    sb = (sb == 2) ? 0 : sb + 1;
  }
  __syncthreads();  // drains vmcnt(0): tail dummies done before LDS reuse

  // ---- epilogue: bias+act in frag domain, LDS transpose, coalesced store
  const int fl = *flag;
  const long Nl = N;
  float bv4[4];
  long gcA[4];
#pragma unroll
  for (int ni = 0; ni < 4; ni++) {
    gcA[ni] = bn + wn + ni * 16 + l16;
    bv4[ni] = biasF32 ? ((const float*)bias)[gcA[ni]] : ldin(bias, gcA[ni], fl);
  }
#pragma unroll
  for (int mi = 0; mi < 4; mi++)
#pragma unroll
    for (int ni = 0; ni < 4; ni++)
#pragma unroll
      for (int r = 0; r < 4; r++) {
        float v = acc[mi][ni][r] + bv4[ni];
        if (act == 1 || (act == 3 && gcA[ni] < 2048)) v = fmaxf(v, 0.f);
        else if (act == 2) v = 0.5f * v * (1.f + erff(v * 0.70710678118654752f));
        acc[mi][ni][r] = v;
      }
  float* sf = (float*)&As[0][0] + wave * 1088;  // 16x68 f32 per wave, disjoint
  const int er = lane >> 2;        // 0..15 row within 16-row slab
  const int ec = (lane & 3) * 16;  // 16-col run
#pragma unroll
  for (int mi = 0; mi < 4; mi++) {
#pragma unroll
    for (int ni = 0; ni < 4; ni++)
#pragma unroll
      for (int r = 0; r < 4; r++)
        sf[(quad * 4 + r) * 68 + ni * 16 + l16] = acc[mi][ni][r];
    // same-wave DS in-order + self-overlapping addresses => ordered
    f32x4 w0 = *(const f32x4*)&sf[er * 68 + ec + 0];
    f32x4 w1 = *(const f32x4*)&sf[er * 68 + ec + 4];
    f32x4 w2 = *(const f32x4*)&sf[er * 68 + ec + 8];
    f32x4 w3 = *(const f32x4*)&sf[er * 68 + ec + 12];
    const long gr = bm + wm + mi * 16 + er;
    const long gc0 = bn + wn + ec;
    const long ib = gr * Nl + gc0;
    if (resMode == 1 || (resMode == 2 && fl)) {
      const f32x4* rp = (const f32x4*)((const float*)res + ib);
      f32x4 r0 = rp[0], r1 = rp[1], r2 = rp[2], r3 = rp[3];
#pragma unroll
      for (int j = 0; j < 4; j++) {
        w0[j] += r0[j]; w1[j] += r1[j]; w2[j] += r2[j]; w3[j] += r3[j];
      }
    } else if (resMode == 2) {
      const short8* rp = (const short8*)((const u16*)res + ib);
      short8 ra = rp[0], rb = rp[1];
#pragma unroll
      for (int j = 0; j < 4; j++) {
        w0[j] += bf2f((u16)ra[j]);
        w1[j] += bf2f((u16)ra[j + 4]);
        w2[j] += bf2f((u16)rb[j]);
        w3[j] += bf2f((u16)rb[j + 4]);
      }
    }
    if (outMode == 1 || (outMode == 2 && fl)) {
      f32x4* op = (f32x4*)((float*)Cout + coff + ib);
      op[0] = w0; op[1] = w1; op[2] = w2; op[3] = w3;
    } else {
      u16 tmp[16];
#pragma unroll
      for (int j = 0; j < 4; j++) {
        tmp[j] = f2bf(w0[j]);
        tmp[j + 4] = f2bf(w1[j]);
        tmp[j + 8] = f2bf(w2[j]);
        tmp[j + 12] = f2bf(w3[j]);
      }
      u16* op;
      if (outMode == 3) {
        const int plane = (int)(bn >> 10);
        u16* dst = (plane == 2) ? (u16*)Cv
                                : ((u16*)Cout + plane * ((long)M << 10));
        op = dst + (gr << 10) + (gc0 & 1023);
      } else {
        op = (u16*)Cout + coff + ib;
      }
      *(short8*)op = *(short8*)&tmp[0];
      *(short8*)(op + 8) = *(short8*)&tmp[8];
    }
  }
}

// ---------------------------------------------------------------------------
// kv partial: per (bh, chunk) accumulate kv_s/kv_c [64x64], ksum_s/c [64]
// kvpart[ch][bh][2][64][64], kspart[ch][bh][2][64]
// ---------------------------------------------------------------------------
__global__ __launch_bounds__(256) void kv_partial(
    const u16* __restrict__ k, const u16* __restrict__ v,
    float* __restrict__ kvpart, float* __restrict__ kspart) {
  const int bh = blockIdx.x;  // 0..63
  const int ch = blockIdx.y;  // 0..NCH-1
  const int b = bh >> 4, h = bh & 15;
  const int tid = threadIdx.x;
  __shared__ float kl[8][64], vl[8][64];
  const int dkq = tid >> 4;  // 0..15
  const int dvq = tid & 15;  // 0..15
  float accS[4][4] = {}, accC[4][4] = {};
  float ksS[4] = {}, ksC[4] = {};
  const int tt = tid >> 5;        // 0..7
  const int cc = (tid & 31) * 2;  // 0..62
  const long base = ((long)b * 4096 + ch * CHT) * EE + h * 64;
  for (int tb = 0; tb < CHT; tb += 8) {
    const long roff = base + (long)(tb + tt) * EE + cc;
    const unsigned int ku = *(const unsigned int*)(k + roff);
    const unsigned int vu = *(const unsigned int*)(v + roff);
    __syncthreads();
    kl[tt][cc] = bf2f((u16)ku);
    kl[tt][cc + 1] = bf2f((u16)(ku >> 16));
    vl[tt][cc] = bf2f((u16)vu);
    vl[tt][cc + 1] = bf2f((u16)(vu >> 16));
    __syncthreads();
#pragma unroll
    for (int j = 0; j < 8; j++) {
      const int t = ch * CHT + tb + j;
      float s, c;
      __sincosf((float)(t + 1) * (PI_F * 0.5f / 4096.f), &s, &c);
      float kk[4], vv[4];
#pragma unroll
      for (int i = 0; i < 4; i++) {
        kk[i] = kl[j][dkq * 4 + i];
        vv[i] = vl[j][dvq * 4 + i];
      }
#pragma unroll
      for (int i = 0; i < 4; i++) {
        const float ks_ = kk[i] * s, kc_ = kk[i] * c;
        ksS[i] += ks_;
        ksC[i] += kc_;
#pragma unroll
        for (int jj = 0; jj < 4; jj++) {
          accS[i][jj] += ks_ * vv[jj];
          accC[i][jj] += kc_ * vv[jj];
        }
      }
    }
  }
  float* outS = kvpart + (((long)ch * 64 + bh) * 2 + 0) * 4096;
  float* outC = outS + 4096;
#pragma unroll
  for (int i = 0; i < 4; i++)
#pragma unroll
    for (int jj = 0; jj < 4; jj++) {
      outS[(dkq * 4 + i) * 64 + dvq * 4 + jj] = accS[i][jj];
      outC[(dkq * 4 + i) * 64 + dvq * 4 + jj] = accC[i][jj];
    }
  if (dvq == 0) {
    float* oS = kspart + ((long)ch * 64 + bh) * 2 * 64;
#pragma unroll
    for (int i = 0; i < 4; i++) {
      oS[dkq * 4 + i] = ksS[i];
      oS[64 + dkq * 4 + i] = ksC[i];
    }
  }
}

// ---------------------------------------------------------------------------
__global__ __launch_bounds__(256) void kv_reduce(
    const float* __restrict__ kvpart, const float* __restrict__ kspart,
    float* __restrict__ kvcomb, float* __restrict__ kscomb) {
  const long KVTOT = 64L * 2 * 4096;  // 524288
  const long KSTOT = 64L * 2 * 64;    // 8192
  const long idx = (long)blockIdx.x * 256 + threadIdx.x;
  if (idx < KVTOT) {
    float s = 0.f;
#pragma unroll
    for (int chn = 0; chn < NCH; chn++) s += kvpart[chn * KVTOT + idx];
    kvcomb[idx] = s;
  } else {
    const long i2 = idx - KVTOT;
    if (i2 < KSTOT) {
      float s = 0.f;
#pragma unroll
      for (int chn = 0; chn < NCH; chn++) s += kspart[chn * KSTOT + i2];
      kscomb[i2] = s;
    }
  }
}

// ---------------------------------------------------------------------------
// apply: out[t,dv] = (s_t*(q.KVs)+c_t*(q.KVc))[dv] / max(s_t*q.kss+c_t*q.ksc,eps)
// ---------------------------------------------------------------------------
__global__ __launch_bounds__(256) void attn_apply(
    const u16* __restrict__ q, const float* __restrict__ kvcomb,
    const float* __restrict__ kscomb, u16* __restrict__ attn) {
  const int bh = blockIdx.x;
  const int b = bh >> 4, h = bh & 15;
  const int t0 = blockIdx.y * 64;
  const int tid = threadIdx.x;
  __shared__ float kvl[2][64][64];
  __shared__ float ksl[2][64];
  __shared__ float ql[64][66];

  const float4* kvsrc = (const float4*)(kvcomb + (long)bh * 8192);
  float4* kvdst = (float4*)&kvl[0][0][0];
#pragma unroll
  for (int i = 0; i < 8; i++) kvdst[tid + 256 * i] = kvsrc[tid + 256 * i];
  if (tid < 32) ((float4*)&ksl[0][0])[tid] = ((const float4*)(kscomb + (long)bh * 128))[tid];
  {
    const int r = tid >> 2;
    const int c = (tid & 3) * 16;
    const u16* qp = q + ((long)b * 4096 + t0 + r) * EE + h * 64 + c;
    const uint4 u0 = *(const uint4*)qp;
    const uint4 u1 = *(const uint4*)(qp + 8);
    unsigned int uu[8] = {u0.x, u0.y, u0.z, u0.w, u1.x, u1.y, u1.z, u1.w};
#pragma unroll
    for (int i = 0; i < 8; i++) {
      ql[r][c + 2 * i] = bf2f((u16)uu[i]);
      ql[r][c + 2 * i + 1] = bf2f((u16)(uu[i] >> 16));
    }
  }
  __syncthreads();

  const int tg = tid >> 4;
  const int dvq = tid & 15;
  const int dv0 = dvq * 4;

  float o1[4][4] = {}, o2[4][4] = {}, zs[4] = {}, zc[4] = {};
  for (int dk = 0; dk < 64; dk++) {
    const float ks0 = ksl[0][dk], ks1 = ksl[1][dk];
    float kv0[4], kv1[4];
#pragma unroll
    for (int j = 0; j < 4; j++) {
      kv0[j] = kvl[0][dk][dv0 + j];
      kv1[j] = kvl[1][dk][dv0 + j];
    }
#pragma unroll
    for (int it = 0; it < 4; it++) {
      const float qv = ql[tg + it * 16][dk];
      zs[it] += qv * ks0;
      zc[it] += qv * ks1;
#pragma unroll
      for (int j = 0; j < 4; j++) {
        o1[it][j] += qv * kv0[j];
        o2[it][j] += qv * kv1[j];
      }
    }
  }
#pragma unroll
  for (int it = 0; it < 4; it++) {
    const int t = t0 + tg + it * 16;
    float s, c;
    __sincosf((float)(t + 1) * (PI_F * 0.5f / 4096.f), &s, &c);
    const float z = s * zs[it] + c * zc[it];
    const float zinv = 1.f / fmaxf(z, 1e-6f);
    ushort4 o4;
    o4.x = f2bf((s * o1[it][0] + c * o2[it][0]) * zinv);
    o4.y = f2bf((s * o1[it][1] + c * o2[it][1]) * zinv);
    o4.z = f2bf((s * o1[it][2] + c * o2[it][2]) * zinv);
    o4.w = f2bf((s * o1[it][3] + c * o2[it][3]) * zinv);
    *(ushort4*)(attn + ((long)b * 4096 + t) * EE + h * 64 + dv0) = o4;
  }
}

// ---------------------------------------------------------------------------
extern "C" void kernel_launch(void* const* d_in, const int* in_sizes, int n_in,
                              void* d_out, int out_size, void* d_ws, size_t ws_size,
                              hipStream_t stream) {
  const void* x = d_in[0];
  const void* ln1w = d_in[1];
  const void* ln1b = d_in[2];
  const void* wq = d_in[3];
  const void* bq = d_in[4];
  const void* wk = d_in[5];
  const void* bk = d_in[6];
  const void* wv = d_in[7];
  const void* bv = d_in[8];
  const void* wo = d_in[9];
  const void* bo = d_in[10];
  const void* ln2w = d_in[11];
  const void* ln2b = d_in[12];
  const void* wfc = d_in[13];
  const void* bfc = d_in[14];
  const void* wproj = d_in[15];
  const void* bproj = d_in[16];

  char* ws = (char*)d_ws;
  size_t off = 0;
  auto alloc = [&](size_t bytes) -> char* {
    char* p = ws + off;
    off += (bytes + 255) & ~((size_t)255);
    return p;
  };
  // footprint identical to the proven 202-MiB baseline layout
  int* flag = (int*)alloc(256);
  u16* wqkvT = (u16*)alloc((size_t)3 * EE * EE * 2);  // [wq^T|wk^T|wv^T] rows
  u16* woT = (u16*)alloc((size_t)EE * EE * 2);
  u16* wfcT = (u16*)alloc((size_t)EE * FF * 2);
  u16* wprojT = (u16*)alloc((size_t)FF * EE * 2);
  float* qkvBias = (float*)alloc(3072 * 4);
  u16* h = (u16*)alloc((size_t)MT * EE * 2);       // 32 MiB
  float* x2 = (float*)alloc((size_t)MT * EE * 4);  // 64 MiB (residual, f32)
  u16* qk2 = (u16*)alloc((size_t)2 * MT * EE * 2); // 64 MiB: q,k planes
  float* kvpart = (float*)alloc((size_t)NCH * 64 * 2 * 64 * 64 * 4);
  float* kspart = (float*)alloc((size_t)NCH * 64 * 2 * 64 * 4);
  float* kvcomb = (float*)alloc((size_t)64 * 2 * 64 * 64 * 4);
  float* kscomb = (float*)alloc((size_t)64 * 2 * 64 * 4);
  const long PL = (long)MT * EE;  // plane stride (elems)
  u16* qb = qk2;            // plane 0
  u16* kb = qk2 + PL;       // plane 1
  u16* vb = (u16*)x2;       // v plane aliases x2[0:32MiB] — x2 dead until WO
                            // gemm, v dead before WO gemm overwrites it
  u16* attnb = kb;          // k-plane dead after kv_partial
  u16* g = qk2;             // q+k planes (64 MiB) dead after WO gemm
  (void)ws_size; (void)in_sizes; (void)n_in; (void)out_size;

  detect_dtype<<<1, 256, 0, stream>>>((const u16*)x, flag);

  transpose_in<<<dim3(16, 16), 256, 0, stream>>>(wq, flag, wqkvT, EE, EE);
  transpose_in<<<dim3(16, 16), 256, 0, stream>>>(wk, flag, wqkvT + (size_t)EE * EE, EE, EE);
  transpose_in<<<dim3(16, 16), 256, 0, stream>>>(wv, flag, wqkvT + (size_t)2 * EE * EE, EE, EE);
  transpose_in<<<dim3(16, 16), 256, 0, stream>>>(wo, flag, woT, EE, EE);
  transpose_in<<<dim3(64, 16), 256, 0, stream>>>(wfc, flag, wfcT, EE, FF);
  transpose_in<<<dim3(16, 64), 256, 0, stream>>>(wproj, flag, wprojT, FF, EE);
  concat3<<<12, 256, 0, stream>>>(bq, bk, bv, flag, qkvBias);

  ln_kernel<<<MT, 256, 0, stream>>>(x, 2, flag, ln1w, ln1b, h);

  // fused QKV: N=3072, relu on q,k planes only; plane-major output
  gemm_bf16<<<dim3(128, 24), 256, 0, stream>>>(h, wqkvT, qkvBias, 1, nullptr, 0,
                                               qk2, vb, 3, 0, flag, MT, 3072, EE, 3);

  kv_partial<<<dim3(64, NCH), 256, 0, stream>>>(kb, vb, kvpart, kspart);
  kv_reduce<<<2080, 256, 0, stream>>>(kvpart, kspart, kvcomb, kscomb);
  attn_apply<<<dim3(64, 64), 256, 0, stream>>>(qb, kvcomb, kscomb, attnb);

  gemm_bf16<<<dim3(128, 8), 256, 0, stream>>>(attnb, woT, bo, 0, x, 2, x2, nullptr,
                                              1, 0, flag, MT, EE, EE, 0);
  ln_kernel<<<MT, 256, 0, stream>>>(x2, 1, flag, ln2w, ln2b, h);

  for (int c = 0; c < 2; c++) {
    const long ro = (long)c * 8192 * EE;
    gemm_bf16<<<dim3(64, 32), 256, 0, stream>>>(h + ro, wfcT, bfc, 0, nullptr, 0,
                                                g, nullptr, 0, 0, flag, 8192, FF, EE, 2);
    gemm_bf16<<<dim3(64, 8), 256, 0, stream>>>(g, wprojT, bproj, 0, x2 + ro, 1,
                                               d_out, nullptr, 2, ro, flag, 8192, EE, FF, 0);
  }
}